// Round 7
// baseline (8458.536 us; speedup 1.0000x reference)
//
#include <hip/hip_runtime.h>
#include <math.h>

// RnnModelInterp R7: single persistent cooperative kernel, 200 steps inside.
// NO grid.sync (R2: 68us/sync). Cross-block exchange (h1, R0 slices) via
// agent-scope relaxed atomics (sc1: bypass per-XCD L2, no invalidation ->
// weights stay L2-resident across all steps). Per-(rt,ct) flags, release/poll,
// row-group-local sync only.
// Block (rt,ct): rows R=rt*8, cols C=ct*64; ct=bid&7 pins weight slice to XCD.
// Wave map (kills R5/R6's 8x L2 redundancy): wave=(ks2 0..7, chh 0..1),
// lane=(r 0..7, q 0..7). The 8 r-lanes share each weight float4 -> coalescer
// dedups to one L2 request. Weights packed [m][ct][k][64] (contiguous rows).
// ws: h1buf[2][131072] | R0buf[2][131072] @262144 | flags[256] @524288 |
//     WP[3*8*512*64] @524544   (total ~5.0 MB)

#define OFF_R0 262144
#define OFF_FLAGS 524288
#define OFF_WP 524544

__device__ __forceinline__ bool nanf_bits(float v) {
  return (__float_as_uint(v) & 0x7fffffffu) > 0x7f800000u;
}
__device__ __forceinline__ float ld_ag(const float* p) {
  return __hip_atomic_load(p, __ATOMIC_RELAXED, __HIP_MEMORY_SCOPE_AGENT);
}
__device__ __forceinline__ void st_ag(float* p, float v) {
  __hip_atomic_store(p, v, __ATOMIC_RELAXED, __HIP_MEMORY_SCOPE_AGENT);
}

__global__ __launch_bounds__(256) void zero_flags(float* __restrict__ ws) {
  ((int*)(ws + OFF_FLAGS))[threadIdx.x] = 0;
}

// WP[((m*8+ct)*512 + k)*64 + c] = Wsrc_m[k*512 + ct*64 + c]
__global__ __launch_bounds__(256) void pack_weights(
    const float* __restrict__ Wih1, const float* __restrict__ Whh1,
    const float* __restrict__ Whh0, float* __restrict__ WP) {
  const unsigned i = blockIdx.x * 256u + threadIdx.x;  // grid 3072 -> 786432
  const unsigned c = i & 63u;
  const unsigned k = (i >> 6) & 511u;
  const unsigned g = i >> 15;  // 0..23
  const unsigned m = g >> 3, ct = g & 7u;
  const float* src = (m == 0) ? Wih1 : (m == 1) ? Whh1 : Whh0;
  WP[i] = src[k * 512u + ct * 64u + c];
}

#define GEMM_J(WA, WB, WC, AJ, BJ)                                          \
  {                                                                         \
    sA.x += (AJ)*WA.x + (BJ)*WB.x; sA.y += (AJ)*WA.y + (BJ)*WB.y;           \
    sA.z += (AJ)*WA.z + (BJ)*WB.z; sA.w += (AJ)*WA.w + (BJ)*WB.w;           \
    sB.x += (AJ)*WC.x; sB.y += (AJ)*WC.y;                                   \
    sB.z += (AJ)*WC.z; sB.w += (AJ)*WC.w;                                   \
  }

__global__ __launch_bounds__(1024, 4) void rnn_persist(
    const float* __restrict__ cat_seq, const float* __restrict__ val_seq,
    const float* __restrict__ Wih0, const float* __restrict__ b0,
    const float* __restrict__ b1, const float* __restrict__ Wc,
    const float* __restrict__ bc, const float* __restrict__ Wm,
    const float* __restrict__ bm, float* __restrict__ out,
    float* __restrict__ ws) {
  __shared__ float h1ps[8 * 516];  // h1(t-1) rows, stride 516 -> r-lanes hit distinct banks
  __shared__ float h0s[8 * 516];
  __shared__ float red[4608];      // [ks2][r][18 float4] k-split partials
  __shared__ float xs[8][68];      // imputed input x(t) per row (+pad[67]=0)

  const int tid = threadIdx.x;
  const int ct = blockIdx.x & 7, rt = blockIdx.x >> 3;
  const int R = rt * 8, C = ct * 64;
  int* flags = (int*)(ws + OFF_FLAGS);
  const float* WPb = ws + OFF_WP;

  const int wave = tid >> 6, lane = tid & 63;
  const int ks2 = wave >> 1, chh = wave & 1;  // k-split 0..7, col-half 0..1
  const int rl = lane >> 3, q = lane & 7;     // row 0..7, col-quad 0..7
  const int kb = ks2 * 64;
  const int cq16 = chh * 8 + q;               // col-quad 0..15

  const float* W1 = WPb + ((size_t)(0 * 8 + ct) * 512 + kb) * 64 + cq16 * 4;
  const float* W2 = WPb + ((size_t)(1 * 8 + ct) * 512 + kb) * 64 + cq16 * 4;
  const float* W3 = WPb + ((size_t)(2 * 8 + ct) * 512 + kb) * 64 + cq16 * 4;
  const float* WmB = Wm + (size_t)kb * 64 + cq16 * 4;

  for (int t = 0; t <= 199; ++t) {
    const bool last = (t == 199);
    if (last && ct != 0) break;  // posted flag=199 at end of t=198; only ct==0 emits out[198]

    if (t > 0) {
      if (tid < 8) {  // wait row-group producers of step t-1
        int g = 0;
        while (__hip_atomic_load(&flags[rt * 8 + tid], __ATOMIC_RELAXED,
                                 __HIP_MEMORY_SCOPE_AGENT) < t &&
               ++g < (1 << 25))
          __builtin_amdgcn_s_sleep(2);
      }
      __syncthreads();
      const float* h1p = ws + (size_t)((t & 1) ^ 1) * 131072;
#pragma unroll
      for (int j = 0; j < 4; ++j) {  // stage h1(t-1)[R..R+7,:] via sc1 loads
        const int i = tid + j * 1024;
        const int r = i >> 9, c = i & 511;
        h1ps[r * 516 + c] = ld_ag(&h1p[(size_t)(R + r) * 512 + c]);
      }
    } else {
      for (int i = tid; i < 8 * 516; i += 1024) h1ps[i] = 0.f;  // h1(-1)=0
      if (tid < 512) {
        const int r = tid >> 6, m = tid & 63;
        xs[r][3 + m] = val_seq[(size_t)(R + r) * 64 + m];
      } else if (tid < 544) {
        const int j = tid - 512, r = j >> 2, e = j & 3;
        if (e < 3) xs[r][e] = cat_seq[(size_t)(R + r) * 3 + e];
        else xs[r][67] = 0.f;
      }
    }
    __syncthreads();

    if (t > 0) {
      // ---- S1a: o_val partials (row rl, cols cq16, k-slice ks2) ----
      if (!last) {
        float4 sA = {0.f, 0.f, 0.f, 0.f};
        const float* hA = &h1ps[rl * 516 + kb];
#pragma unroll 4
        for (int k4 = 0; k4 < 16; ++k4) {
          const float4 h = *(const float4*)(hA + k4 * 4);
          const float4 w0 = *(const float4*)(WmB + (size_t)(k4 * 4 + 0) * 64);
          const float4 w1 = *(const float4*)(WmB + (size_t)(k4 * 4 + 1) * 64);
          const float4 w2 = *(const float4*)(WmB + (size_t)(k4 * 4 + 2) * 64);
          const float4 w3 = *(const float4*)(WmB + (size_t)(k4 * 4 + 3) * 64);
          sA.x += h.x * w0.x + h.y * w1.x + h.z * w2.x + h.w * w3.x;
          sA.y += h.x * w0.y + h.y * w1.y + h.z * w2.y + h.w * w3.y;
          sA.z += h.x * w0.z + h.y * w1.z + h.z * w2.z + h.w * w3.z;
          sA.w += h.x * w0.w + h.y * w1.w + h.z * w2.w + h.w * w3.w;
        }
        *(float4*)&red[((ks2 * 8 + rl) * 18 + cq16) * 4] = sA;
      }
      // ---- S1b: cat head + softmax (chh==0 waves; row = ks2) ----
      if (chh == 0) {
        const int rr = ks2;
        float c0 = 0.f, c1 = 0.f, c2 = 0.f;
        const float* hp = &h1ps[rr * 516 + lane * 8];
        const float* wp = Wc + (size_t)lane * 24;
#pragma unroll
        for (int kk = 0; kk < 8; ++kk) {
          const float h = hp[kk];
          c0 += h * wp[kk * 3 + 0];
          c1 += h * wp[kk * 3 + 1];
          c2 += h * wp[kk * 3 + 2];
        }
#pragma unroll
        for (int off = 32; off >= 1; off >>= 1) {
          c0 += __shfl_down(c0, off);
          c1 += __shfl_down(c1, off);
          c2 += __shfl_down(c2, off);
        }
        if (lane == 0) {
          c0 += bc[0]; c1 += bc[1]; c2 += bc[2];
          const float mx = fmaxf(c0, fmaxf(c1, c2));
          const float e0 = expf(c0 - mx), e1 = expf(c1 - mx), e2 = expf(c2 - mx);
          const float inv = 1.f / (e0 + e1 + e2);
          const float p0 = e0 * inv, p1 = e1 * inv, p2 = e2 * inv;
          if (ct == 0) {
            const size_t ob = (size_t)(t - 1) * 768 + (size_t)(R + rr) * 3;
            out[ob] = p0; out[ob + 1] = p1; out[ob + 2] = p2;
          }
          const size_t cb = (size_t)t * 768 + (size_t)(R + rr) * 3;
          const float g0 = cat_seq[cb], g1 = cat_seq[cb + 1], g2 = cat_seq[cb + 2];
          xs[rr][0] = nanf_bits(g0) ? p0 : g0;
          xs[rr][1] = nanf_bits(g1) ? p1 : g1;
          xs[rr][2] = nanf_bits(g2) ? p2 : g2;
        }
      }
      __syncthreads();
      if (last) break;  // ct==0: out[198] written, done
      // ---- S1c: finalize o_val + impute vals (tid<128: (r, cq)) ----
      if (tid < 128) {
        const int r = tid >> 4, cq = tid & 15;
        float4 s = {0.f, 0.f, 0.f, 0.f};
#pragma unroll
        for (int k = 0; k < 8; ++k) {
          const float4 v = *(const float4*)&red[((k * 8 + r) * 18 + cq) * 4];
          s.x += v.x; s.y += v.y; s.z += v.z; s.w += v.w;
        }
        const int m0 = cq * 4;
        const float4 bmv = *(const float4*)&bm[m0];
        const float4 raw = *(const float4*)&val_seq[(size_t)t * 16384 +
                                                    (size_t)(R + r) * 64 + m0];
        const float ov0 = s.x + bmv.x + xs[r][3 + m0 + 0];
        const float ov1 = s.y + bmv.y + xs[r][3 + m0 + 1];
        const float ov2 = s.z + bmv.z + xs[r][3 + m0 + 2];
        const float ov3 = s.w + bmv.w + xs[r][3 + m0 + 3];
        xs[r][3 + m0 + 0] = nanf_bits(raw.x) ? ov0 : raw.x;
        xs[r][3 + m0 + 1] = nanf_bits(raw.y) ? ov1 : raw.y;
        xs[r][3 + m0 + 2] = nanf_bits(raw.z) ? ov2 : raw.z;
        xs[r][3 + m0 + 3] = nanf_bits(raw.w) ? ov3 : raw.w;
      }
      __syncthreads();
    }

    // ---- S2: h0(t) = tanh(x@Wih0 + R0p + b0) -> h0s (LDS only) ----
    {
      const int c = tid & 511, r0 = (tid >> 9) * 4;
      const float* R0p = ws + OFF_R0 + (size_t)((t & 1) ^ 1) * 131072;
      const float bv = b0[c];
      float a0 = bv, a1 = bv, a2 = bv, a3 = bv;
      if (t > 0) {
        a0 += ld_ag(&R0p[(size_t)(R + r0 + 0) * 512 + c]);
        a1 += ld_ag(&R0p[(size_t)(R + r0 + 1) * 512 + c]);
        a2 += ld_ag(&R0p[(size_t)(R + r0 + 2) * 512 + c]);
        a3 += ld_ag(&R0p[(size_t)(R + r0 + 3) * 512 + c]);
      }
      const float* wp = Wih0 + c;
#pragma unroll 4
      for (int k4 = 0; k4 < 16; ++k4) {
        const float4 x0 = *(const float4*)&xs[r0 + 0][k4 * 4];
        const float4 x1 = *(const float4*)&xs[r0 + 1][k4 * 4];
        const float4 x2 = *(const float4*)&xs[r0 + 2][k4 * 4];
        const float4 x3 = *(const float4*)&xs[r0 + 3][k4 * 4];
        const float w0 = wp[(size_t)(k4 * 4 + 0) * 512];
        const float w1 = wp[(size_t)(k4 * 4 + 1) * 512];
        const float w2 = wp[(size_t)(k4 * 4 + 2) * 512];
        const float w3 = wp[(size_t)(k4 * 4 + 3) * 512];
        a0 += x0.x * w0 + x0.y * w1 + x0.z * w2 + x0.w * w3;
        a1 += x1.x * w0 + x1.y * w1 + x1.z * w2 + x1.w * w3;
        a2 += x2.x * w0 + x2.y * w1 + x2.z * w2 + x2.w * w3;
        a3 += x3.x * w0 + x3.y * w1 + x3.z * w2 + x3.w * w3;
      }
      {  // tail k = 64..66
        const float4 x0 = *(const float4*)&xs[r0 + 0][64];
        const float4 x1 = *(const float4*)&xs[r0 + 1][64];
        const float4 x2 = *(const float4*)&xs[r0 + 2][64];
        const float4 x3 = *(const float4*)&xs[r0 + 3][64];
        const float w0 = wp[64 * 512], w1 = wp[65 * 512], w2 = wp[66 * 512];
        a0 += x0.x * w0 + x0.y * w1 + x0.z * w2;
        a1 += x1.x * w0 + x1.y * w1 + x1.z * w2;
        a2 += x2.x * w0 + x2.y * w1 + x2.z * w2;
        a3 += x3.x * w0 + x3.y * w1 + x3.z * w2;
      }
      h0s[(r0 + 0) * 516 + c] = tanhf(a0);
      h0s[(r0 + 1) * 516 + c] = tanhf(a1);
      h0s[(r0 + 2) * 516 + c] = tanhf(a2);
      h0s[(r0 + 3) * 516 + c] = tanhf(a3);
    }
    __syncthreads();

    // ---- S3: sA = h0@Wih1 + h1p@Whh1 ; sB = h0@Whh0 (row rl, quad cq16) ----
    float4 sA = {0.f, 0.f, 0.f, 0.f}, sB = {0.f, 0.f, 0.f, 0.f};
    {
      const float* hA = &h0s[rl * 516 + kb];
      const float* hB = &h1ps[rl * 516 + kb];
#pragma unroll 2
      for (int k4 = 0; k4 < 16; ++k4) {
        const float4 a = *(const float4*)(hA + k4 * 4);
        const float4 b = *(const float4*)(hB + k4 * 4);
        {
          const float4 w1 = *(const float4*)(W1 + (size_t)(k4 * 4 + 0) * 64);
          const float4 w2 = *(const float4*)(W2 + (size_t)(k4 * 4 + 0) * 64);
          const float4 w3 = *(const float4*)(W3 + (size_t)(k4 * 4 + 0) * 64);
          GEMM_J(w1, w2, w3, a.x, b.x);
        }
        {
          const float4 w1 = *(const float4*)(W1 + (size_t)(k4 * 4 + 1) * 64);
          const float4 w2 = *(const float4*)(W2 + (size_t)(k4 * 4 + 1) * 64);
          const float4 w3 = *(const float4*)(W3 + (size_t)(k4 * 4 + 1) * 64);
          GEMM_J(w1, w2, w3, a.y, b.y);
        }
        {
          const float4 w1 = *(const float4*)(W1 + (size_t)(k4 * 4 + 2) * 64);
          const float4 w2 = *(const float4*)(W2 + (size_t)(k4 * 4 + 2) * 64);
          const float4 w3 = *(const float4*)(W3 + (size_t)(k4 * 4 + 2) * 64);
          GEMM_J(w1, w2, w3, a.z, b.z);
        }
        {
          const float4 w1 = *(const float4*)(W1 + (size_t)(k4 * 4 + 3) * 64);
          const float4 w2 = *(const float4*)(W2 + (size_t)(k4 * 4 + 3) * 64);
          const float4 w3 = *(const float4*)(W3 + (size_t)(k4 * 4 + 3) * 64);
          GEMM_J(w1, w2, w3, a.w, b.w);
        }
      }
    }
    // two-pass k-split reduce through red (LDS budget)
    *(float4*)&red[((ks2 * 8 + rl) * 18 + cq16) * 4] = sA;
    __syncthreads();
    if (tid < 128) {
      const int r = tid >> 4, cq = tid & 15;
      float4 s = {0.f, 0.f, 0.f, 0.f};
#pragma unroll
      for (int k = 0; k < 8; ++k) {
        const float4 v = *(const float4*)&red[((k * 8 + r) * 18 + cq) * 4];
        s.x += v.x; s.y += v.y; s.z += v.z; s.w += v.w;
      }
      const int col = C + cq * 4;
      const float4 b1v = *(const float4*)&b1[col];
      float* h1w = ws + (size_t)(t & 1) * 131072;
      st_ag(&h1w[(size_t)(R + r) * 512 + col + 0], tanhf(s.x + b1v.x));
      st_ag(&h1w[(size_t)(R + r) * 512 + col + 1], tanhf(s.y + b1v.y));
      st_ag(&h1w[(size_t)(R + r) * 512 + col + 2], tanhf(s.z + b1v.z));
      st_ag(&h1w[(size_t)(R + r) * 512 + col + 3], tanhf(s.w + b1v.w));
    }
    __syncthreads();
    *(float4*)&red[((ks2 * 8 + rl) * 18 + cq16) * 4] = sB;
    __syncthreads();
    if (tid < 128) {
      const int r = tid >> 4, cq = tid & 15;
      float4 s = {0.f, 0.f, 0.f, 0.f};
#pragma unroll
      for (int k = 0; k < 8; ++k) {
        const float4 v = *(const float4*)&red[((k * 8 + r) * 18 + cq) * 4];
        s.x += v.x; s.y += v.y; s.z += v.z; s.w += v.w;
      }
      const int col = C + cq * 4;
      float* R0w = ws + OFF_R0 + (size_t)(t & 1) * 131072;
      st_ag(&R0w[(size_t)(R + r) * 512 + col + 0], s.x);
      st_ag(&R0w[(size_t)(R + r) * 512 + col + 1], s.y);
      st_ag(&R0w[(size_t)(R + r) * 512 + col + 2], s.z);
      st_ag(&R0w[(size_t)(R + r) * 512 + col + 3], s.w);
    }
    __syncthreads();  // drains all sc1 stores (vmcnt0 at barrier)
    if (tid == 0)
      __hip_atomic_store(&flags[rt * 8 + ct], t + 1, __ATOMIC_RELEASE,
                         __HIP_MEMORY_SCOPE_AGENT);
  }
}

extern "C" void kernel_launch(void* const* d_in, const int* in_sizes, int n_in,
                              void* d_out, int out_size, void* d_ws, size_t ws_size,
                              hipStream_t stream) {
  const float* cat_seq = (const float*)d_in[0];
  const float* val_seq = (const float*)d_in[1];
  const float* Wih0 = (const float*)d_in[2];
  const float* Whh0 = (const float*)d_in[3];
  const float* b0 = (const float*)d_in[4];
  const float* Wih1 = (const float*)d_in[5];
  const float* Whh1 = (const float*)d_in[6];
  const float* b1 = (const float*)d_in[7];
  const float* Wc = (const float*)d_in[8];
  const float* bc = (const float*)d_in[9];
  const float* Wm = (const float*)d_in[10];
  const float* bm = (const float*)d_in[11];
  float* ws = (float*)d_ws;
  float* out = (float*)d_out;

  hipLaunchKernelGGL(zero_flags, dim3(1), dim3(256), 0, stream, ws);
  hipLaunchKernelGGL(pack_weights, dim3(3072), dim3(256), 0, stream,
                     Wih1, Whh1, Whh0, ws + OFF_WP);
  void* args[] = {(void*)&cat_seq, (void*)&val_seq, (void*)&Wih0, (void*)&b0,
                  (void*)&b1,      (void*)&Wc,      (void*)&bc,   (void*)&Wm,
                  (void*)&bm,      (void*)&out,     (void*)&ws};
  hipLaunchCooperativeKernel((void*)rnn_persist, dim3(256), dim3(1024), args,
                             0, stream);
}

// Round 11
// 8015.396 us; speedup vs baseline: 1.0553x; 1.0553x over previous
//
#include <hip/hip_runtime.h>
#include <math.h>

// RnnModelInterp R11 = R10 + store-drain fix.
// ROOT CAUSE of R9/R10 failures: inline-asm global_store ops are invisible to
// SIInsertWaitcnts -> the s_waitcnt the compiler emits before s_barrier and
// before the RELEASE flag store does NOT cover them. Flag became visible while
// h1/R0 data stores were in flight -> consumers read stale state (absmax
// 0.09-0.13, run-varying). Fix: explicit `s_waitcnt vmcnt(0)` in the producer
// waves after the last exchange store, before the final barrier + flag post.
// Structure (unchanged from R10): persistent cooperative kernel, 200 steps,
// no grid.sync; 16B sc0-sc1 exchange; per-row-group flag handshake;
// ct=bid&7 pins weight slices to XCDs.
// ws: h1buf[2][131072] | R0buf[2][131072] @262144 | flags[256] @524288 |
//     WP[3*8*512*64] @524544

#define OFF_R0 262144
#define OFF_FLAGS 524288
#define OFF_WP 524544

typedef float vf4 __attribute__((ext_vector_type(4)));

__device__ __forceinline__ bool nanf_bits(float v) {
  return (__float_as_uint(v) & 0x7fffffffu) > 0x7f800000u;
}

// two coherent (sc0 sc1) 16B loads, one drain (drain inside the asm: the
// compiler cannot insert waits for asm-internal VMEM ops).
__device__ __forceinline__ void ldx4x2_ag(const float* pa, const float* pb,
                                          vf4& va, vf4& vb) {
  asm volatile(
      "global_load_dwordx4 %0, %2, off sc0 sc1\n\t"
      "global_load_dwordx4 %1, %3, off sc0 sc1\n\t"
      "s_waitcnt vmcnt(0)"
      : "=&v"(va), "=&v"(vb)
      : "v"(pa), "v"(pb)
      : "memory");
}

__device__ __forceinline__ void stx4_ag(float* p, vf4 v) {
  asm volatile("global_store_dwordx4 %0, %1, off sc0 sc1" ::"v"(p), "v"(v)
               : "memory");
}

// drain THIS wave's outstanding asm stores (compiler can't do it for us)
__device__ __forceinline__ void drain_stores() {
  asm volatile("s_waitcnt vmcnt(0)" ::: "memory");
}

__global__ __launch_bounds__(256) void zero_flags(float* __restrict__ ws) {
  ((int*)(ws + OFF_FLAGS))[threadIdx.x] = 0;
}

// WP[((m*8+ct)*512 + k)*64 + c] = Wsrc_m[k*512 + ct*64 + c]
__global__ __launch_bounds__(256) void pack_weights(
    const float* __restrict__ Wih1, const float* __restrict__ Whh1,
    const float* __restrict__ Whh0, float* __restrict__ WP) {
  const unsigned i = blockIdx.x * 256u + threadIdx.x;  // grid 3072 -> 786432
  const unsigned c = i & 63u;
  const unsigned k = (i >> 6) & 511u;
  const unsigned g = i >> 15;  // 0..23
  const unsigned m = g >> 3, ct = g & 7u;
  const float* src = (m == 0) ? Wih1 : (m == 1) ? Whh1 : Whh0;
  WP[i] = src[k * 512u + ct * 64u + c];
}

#define GEMM_J(WA, WB, WC, AJ, BJ)                                          \
  {                                                                         \
    sA.x += (AJ)*WA.x + (BJ)*WB.x; sA.y += (AJ)*WA.y + (BJ)*WB.y;           \
    sA.z += (AJ)*WA.z + (BJ)*WB.z; sA.w += (AJ)*WA.w + (BJ)*WB.w;           \
    sB.x += (AJ)*WC.x; sB.y += (AJ)*WC.y;                                   \
    sB.z += (AJ)*WC.z; sB.w += (AJ)*WC.w;                                   \
  }

__global__ __launch_bounds__(1024, 4) void rnn_persist(
    const float* __restrict__ cat_seq, const float* __restrict__ val_seq,
    const float* __restrict__ Wih0, const float* __restrict__ b0,
    const float* __restrict__ b1, const float* __restrict__ Wc,
    const float* __restrict__ bc, const float* __restrict__ Wm,
    const float* __restrict__ bm, float* __restrict__ out,
    float* __restrict__ ws) {
  __shared__ float h1ps[8 * 516];  // staged h1(t-1); stride 516
  __shared__ float h0s[8 * 516];   // staged R0(t-1), then overwritten by h0(t)
  __shared__ float red[4608];      // [ks2][rl][18 float4] k-split partials
  __shared__ float xs[8][68];      // imputed input x per row (val carry)

  const int tid = threadIdx.x;
  const int ct = blockIdx.x & 7, rt = blockIdx.x >> 3;
  const int R = rt * 8, C = ct * 64;
  int* flags = (int*)(ws + OFF_FLAGS);
  const float* WPb = ws + OFF_WP;

  const int wave = tid >> 6, lane = tid & 63;
  const int ks2 = wave >> 1, chh = wave & 1;  // k-split 0..7, col-half 0..1
  const int rl = lane >> 3, q = lane & 7;     // row 0..7, col-quad 0..7
  const int kb = ks2 * 64;
  const int cq16 = chh * 8 + q;               // col-quad 0..15

  const float* W1 = WPb + ((size_t)(0 * 8 + ct) * 512 + kb) * 64 + cq16 * 4;
  const float* W2 = WPb + ((size_t)(1 * 8 + ct) * 512 + kb) * 64 + cq16 * 4;
  const float* W3 = WPb + ((size_t)(2 * 8 + ct) * 512 + kb) * 64 + cq16 * 4;
  const float* WmB = Wm + (size_t)kb * 64 + cq16 * 4;

  // staging map: thread -> (row sr, float-offset sc4)
  const int sr = tid >> 7, sc4 = (tid & 127) * 4;

  for (int t = 0; t <= 199; ++t) {
    const bool last = (t == 199);
    if (last && ct != 0) break;  // their flag(199) already posted at t=198

    if (t > 0) {
      if (tid < 8) {  // wait all 8 producers of this row-group for step t-1
        int g = 0;
        while (__hip_atomic_load(&flags[rt * 8 + tid], __ATOMIC_RELAXED,
                                 __HIP_MEMORY_SCOPE_AGENT) < t &&
               ++g < (1 << 25))
          __builtin_amdgcn_s_sleep(8);
      }
      __syncthreads();
      const float* h1p = ws + (size_t)((t & 1) ^ 1) * 131072;
      const float* R0p = ws + OFF_R0 + (size_t)((t & 1) ^ 1) * 131072;
      vf4 va, vb;  // one 16B slice of h1p and R0p per thread
      ldx4x2_ag(&h1p[(size_t)(R + sr) * 512 + sc4],
                &R0p[(size_t)(R + sr) * 512 + sc4], va, vb);
      *(vf4*)&h1ps[sr * 516 + sc4] = va;
      *(vf4*)&h0s[sr * 516 + sc4] = vb;
    } else {
      for (int i = tid; i < 8 * 516; i += 1024) h1ps[i] = 0.f;  // h1(-1)=0
      if (tid < 512) {
        const int r = tid >> 6, m = tid & 63;
        xs[r][3 + m] = val_seq[(size_t)(R + r) * 64 + m];
      } else if (tid < 544) {
        const int j = tid - 512, r = j >> 2, e = j & 3;  // rows 0..7
        if (e < 3) xs[r][e] = cat_seq[(size_t)(R + r) * 3 + e];
        else xs[r][67] = 0.f;
      }
    }
    __syncthreads();

    if (t > 0) {
      // ---- S1a: o_val partials (row rl, col-quad cq16, k-slice ks2) ----
      if (!last) {
        float4 sA = {0.f, 0.f, 0.f, 0.f};
        const float* hA = &h1ps[rl * 516 + kb];
#pragma unroll 4
        for (int k4 = 0; k4 < 16; ++k4) {
          const float4 h = *(const float4*)(hA + k4 * 4);
          const float4 w0 = *(const float4*)(WmB + (size_t)(k4 * 4 + 0) * 64);
          const float4 w1 = *(const float4*)(WmB + (size_t)(k4 * 4 + 1) * 64);
          const float4 w2 = *(const float4*)(WmB + (size_t)(k4 * 4 + 2) * 64);
          const float4 w3 = *(const float4*)(WmB + (size_t)(k4 * 4 + 3) * 64);
          sA.x += h.x * w0.x + h.y * w1.x + h.z * w2.x + h.w * w3.x;
          sA.y += h.x * w0.y + h.y * w1.y + h.z * w2.y + h.w * w3.y;
          sA.z += h.x * w0.z + h.y * w1.z + h.z * w2.z + h.w * w3.z;
          sA.w += h.x * w0.w + h.y * w1.w + h.z * w2.w + h.w * w3.w;
        }
        *(float4*)&red[((ks2 * 8 + rl) * 18 + cq16) * 4] = sA;
      }
      // ---- S1b: cat head + softmax (chh==0 waves; row = ks2) ----
      if (chh == 0) {
        const int rr = ks2;
        float c0 = 0.f, c1 = 0.f, c2 = 0.f;
        const float* hp = &h1ps[rr * 516 + lane * 8];
        const float* wp = Wc + (size_t)lane * 24;
#pragma unroll
        for (int kk = 0; kk < 8; ++kk) {
          const float h = hp[kk];
          c0 += h * wp[kk * 3 + 0];
          c1 += h * wp[kk * 3 + 1];
          c2 += h * wp[kk * 3 + 2];
        }
#pragma unroll
        for (int off = 32; off >= 1; off >>= 1) {
          c0 += __shfl_down(c0, off);
          c1 += __shfl_down(c1, off);
          c2 += __shfl_down(c2, off);
        }
        if (lane == 0) {
          c0 += bc[0]; c1 += bc[1]; c2 += bc[2];
          const float mx = fmaxf(c0, fmaxf(c1, c2));
          const float e0 = expf(c0 - mx), e1 = expf(c1 - mx), e2 = expf(c2 - mx);
          const float inv = 1.f / (e0 + e1 + e2);
          const float p0 = e0 * inv, p1 = e1 * inv, p2 = e2 * inv;
          if (ct == 0) {
            const size_t ob = (size_t)(t - 1) * 768 + (size_t)(R + rr) * 3;
            out[ob] = p0; out[ob + 1] = p1; out[ob + 2] = p2;
          }
          const size_t cb = (size_t)t * 768 + (size_t)(R + rr) * 3;
          const float g0 = cat_seq[cb], g1 = cat_seq[cb + 1], g2 = cat_seq[cb + 2];
          xs[rr][0] = nanf_bits(g0) ? p0 : g0;
          xs[rr][1] = nanf_bits(g1) ? p1 : g1;
          xs[rr][2] = nanf_bits(g2) ? p2 : g2;
        }
      }
      __syncthreads();
      if (last) break;  // ct==0: out[198] written, done
      // ---- S1c: finalize o_val + impute vals (tid<128: (r, cq)) ----
      if (tid < 128) {
        const int r = tid >> 4, cq = tid & 15;
        float4 s = {0.f, 0.f, 0.f, 0.f};
#pragma unroll
        for (int k = 0; k < 8; ++k) {
          const float4 v = *(const float4*)&red[((k * 8 + r) * 18 + cq) * 4];
          s.x += v.x; s.y += v.y; s.z += v.z; s.w += v.w;
        }
        const int m0 = cq * 4;
        const float4 bmv = *(const float4*)&bm[m0];
        const float4 raw = *(const float4*)&val_seq[(size_t)t * 16384 +
                                                    (size_t)(R + r) * 64 + m0];
        const float ov0 = s.x + bmv.x + xs[r][3 + m0 + 0];
        const float ov1 = s.y + bmv.y + xs[r][3 + m0 + 1];
        const float ov2 = s.z + bmv.z + xs[r][3 + m0 + 2];
        const float ov3 = s.w + bmv.w + xs[r][3 + m0 + 3];
        xs[r][3 + m0 + 0] = nanf_bits(raw.x) ? ov0 : raw.x;
        xs[r][3 + m0 + 1] = nanf_bits(raw.y) ? ov1 : raw.y;
        xs[r][3 + m0 + 2] = nanf_bits(raw.z) ? ov2 : raw.z;
        xs[r][3 + m0 + 3] = nanf_bits(raw.w) ? ov3 : raw.w;
      }
      __syncthreads();
    }

    // ---- S2: h0(t) = tanh(x@Wih0 + R0p + b0) -> h0s ----
    // thread (c, 4 rows); R0p staged in h0s -> thread-private RMW, race-free.
    {
      const int c = tid & 511, r0 = (tid >> 9) * 4;
      const float bv = b0[c];
      float a0 = bv, a1 = bv, a2 = bv, a3 = bv;
      if (t > 0) {
        a0 += h0s[(r0 + 0) * 516 + c];
        a1 += h0s[(r0 + 1) * 516 + c];
        a2 += h0s[(r0 + 2) * 516 + c];
        a3 += h0s[(r0 + 3) * 516 + c];
      }
      const float* wp = Wih0 + c;
#pragma unroll 4
      for (int k4 = 0; k4 < 16; ++k4) {
        const float4 x0 = *(const float4*)&xs[r0 + 0][k4 * 4];
        const float4 x1 = *(const float4*)&xs[r0 + 1][k4 * 4];
        const float4 x2 = *(const float4*)&xs[r0 + 2][k4 * 4];
        const float4 x3 = *(const float4*)&xs[r0 + 3][k4 * 4];
        const float w0 = wp[(size_t)(k4 * 4 + 0) * 512];
        const float w1 = wp[(size_t)(k4 * 4 + 1) * 512];
        const float w2 = wp[(size_t)(k4 * 4 + 2) * 512];
        const float w3 = wp[(size_t)(k4 * 4 + 3) * 512];
        a0 += x0.x * w0 + x0.y * w1 + x0.z * w2 + x0.w * w3;
        a1 += x1.x * w0 + x1.y * w1 + x1.z * w2 + x1.w * w3;
        a2 += x2.x * w0 + x2.y * w1 + x2.z * w2 + x2.w * w3;
        a3 += x3.x * w0 + x3.y * w1 + x3.z * w2 + x3.w * w3;
      }
      {  // tail k = 64..66
        const float w0 = wp[64 * 512], w1 = wp[65 * 512], w2 = wp[66 * 512];
        a0 += xs[r0 + 0][64] * w0 + xs[r0 + 0][65] * w1 + xs[r0 + 0][66] * w2;
        a1 += xs[r0 + 1][64] * w0 + xs[r0 + 1][65] * w1 + xs[r0 + 1][66] * w2;
        a2 += xs[r0 + 2][64] * w0 + xs[r0 + 2][65] * w1 + xs[r0 + 2][66] * w2;
        a3 += xs[r0 + 3][64] * w0 + xs[r0 + 3][65] * w1 + xs[r0 + 3][66] * w2;
      }
      __syncthreads();  // all R0p reads done before overwriting h0s
      h0s[(r0 + 0) * 516 + c] = tanhf(a0);
      h0s[(r0 + 1) * 516 + c] = tanhf(a1);
      h0s[(r0 + 2) * 516 + c] = tanhf(a2);
      h0s[(r0 + 3) * 516 + c] = tanhf(a3);
    }
    __syncthreads();

    // ---- S3: sA = h0@Wih1 + h1p@Whh1 ; sB = h0@Whh0 ----
    float4 sA = {0.f, 0.f, 0.f, 0.f}, sB = {0.f, 0.f, 0.f, 0.f};
    {
      const float* hA = &h0s[rl * 516 + kb];
      const float* hB = &h1ps[rl * 516 + kb];
#pragma unroll 2
      for (int k4 = 0; k4 < 16; ++k4) {
        const float4 a = *(const float4*)(hA + k4 * 4);
        const float4 b = *(const float4*)(hB + k4 * 4);
        {
          const float4 w1 = *(const float4*)(W1 + (size_t)(k4 * 4 + 0) * 64);
          const float4 w2 = *(const float4*)(W2 + (size_t)(k4 * 4 + 0) * 64);
          const float4 w3 = *(const float4*)(W3 + (size_t)(k4 * 4 + 0) * 64);
          GEMM_J(w1, w2, w3, a.x, b.x);
        }
        {
          const float4 w1 = *(const float4*)(W1 + (size_t)(k4 * 4 + 1) * 64);
          const float4 w2 = *(const float4*)(W2 + (size_t)(k4 * 4 + 1) * 64);
          const float4 w3 = *(const float4*)(W3 + (size_t)(k4 * 4 + 1) * 64);
          GEMM_J(w1, w2, w3, a.y, b.y);
        }
        {
          const float4 w1 = *(const float4*)(W1 + (size_t)(k4 * 4 + 2) * 64);
          const float4 w2 = *(const float4*)(W2 + (size_t)(k4 * 4 + 2) * 64);
          const float4 w3 = *(const float4*)(W3 + (size_t)(k4 * 4 + 2) * 64);
          GEMM_J(w1, w2, w3, a.z, b.z);
        }
        {
          const float4 w1 = *(const float4*)(W1 + (size_t)(k4 * 4 + 3) * 64);
          const float4 w2 = *(const float4*)(W2 + (size_t)(k4 * 4 + 3) * 64);
          const float4 w3 = *(const float4*)(W3 + (size_t)(k4 * 4 + 3) * 64);
          GEMM_J(w1, w2, w3, a.w, b.w);
        }
      }
    }
    // two-pass k-split reduce through red
    *(float4*)&red[((ks2 * 8 + rl) * 18 + cq16) * 4] = sA;
    __syncthreads();
    if (tid < 128) {
      const int r = tid >> 4, cq = tid & 15;
      float4 s = {0.f, 0.f, 0.f, 0.f};
#pragma unroll
      for (int k = 0; k < 8; ++k) {
        const float4 v = *(const float4*)&red[((k * 8 + r) * 18 + cq) * 4];
        s.x += v.x; s.y += v.y; s.z += v.z; s.w += v.w;
      }
      const int col = C + cq * 4;
      const float4 b1v = *(const float4*)&b1[col];
      float* h1w = ws + (size_t)(t & 1) * 131072;
      vf4 o;
      o.x = tanhf(s.x + b1v.x);
      o.y = tanhf(s.y + b1v.y);
      o.z = tanhf(s.z + b1v.z);
      o.w = tanhf(s.w + b1v.w);
      stx4_ag(&h1w[(size_t)(R + r) * 512 + col], o);
    }
    __syncthreads();
    *(float4*)&red[((ks2 * 8 + rl) * 18 + cq16) * 4] = sB;
    __syncthreads();
    if (tid < 128) {
      const int r = tid >> 4, cq = tid & 15;
      vf4 s = {0.f, 0.f, 0.f, 0.f};
#pragma unroll
      for (int k = 0; k < 8; ++k) {
        const float4 v = *(const float4*)&red[((k * 8 + r) * 18 + cq) * 4];
        s.x += v.x; s.y += v.y; s.z += v.z; s.w += v.w;
      }
      const int col = C + cq * 4;
      float* R0w = ws + OFF_R0 + (size_t)(t & 1) * 131072;
      stx4_ag(&R0w[(size_t)(R + r) * 512 + col], s);
      // FIX: drain this wave's asm stores (h1w + R0w) — the compiler cannot
      // track asm-internal VMEM ops, so barrier/release waits don't cover them.
      drain_stores();
    }
    __syncthreads();
    if (tid == 0)
      __hip_atomic_store(&flags[rt * 8 + ct], t + 1, __ATOMIC_RELEASE,
                         __HIP_MEMORY_SCOPE_AGENT);
  }
}

extern "C" void kernel_launch(void* const* d_in, const int* in_sizes, int n_in,
                              void* d_out, int out_size, void* d_ws, size_t ws_size,
                              hipStream_t stream) {
  const float* cat_seq = (const float*)d_in[0];
  const float* val_seq = (const float*)d_in[1];
  const float* Wih0 = (const float*)d_in[2];
  const float* Whh0 = (const float*)d_in[3];
  const float* b0 = (const float*)d_in[4];
  const float* Wih1 = (const float*)d_in[5];
  const float* Whh1 = (const float*)d_in[6];
  const float* b1 = (const float*)d_in[7];
  const float* Wc = (const float*)d_in[8];
  const float* bc = (const float*)d_in[9];
  const float* Wm = (const float*)d_in[10];
  const float* bm = (const float*)d_in[11];
  float* ws = (float*)d_ws;
  float* out = (float*)d_out;

  hipLaunchKernelGGL(zero_flags, dim3(1), dim3(256), 0, stream, ws);
  hipLaunchKernelGGL(pack_weights, dim3(3072), dim3(256), 0, stream,
                     Wih1, Whh1, Whh0, ws + OFF_WP);
  void* args[] = {(void*)&cat_seq, (void*)&val_seq, (void*)&Wih0, (void*)&b0,
                  (void*)&b1,      (void*)&Wc,      (void*)&bc,   (void*)&Wm,
                  (void*)&bm,      (void*)&out,     (void*)&ws};
  hipLaunchCooperativeKernel((void*)rnn_persist, dim3(256), dim3(1024), args,
                             0, stream);
}